// Round 5
// baseline (297.322 us; speedup 1.0000x reference)
//
#include <hip/hip_runtime.h>

typedef __bf16 bf16;
typedef __bf16 bf16x4 __attribute__((ext_vector_type(4)));
typedef __bf16 bf16x8 __attribute__((ext_vector_type(8)));
typedef float  f32x4  __attribute__((ext_vector_type(4)));
typedef unsigned int u32;
typedef unsigned int u32x2 __attribute__((ext_vector_type(2)));
typedef unsigned int u32x4 __attribute__((ext_vector_type(4)));

#define LOG2E 1.44269504088896340736f
#define EXP_SC (0.125f * LOG2E)   // folded into Q at the QKV-GEMM epilogue

#if __has_builtin(__builtin_amdgcn_exp2f)
#define EXP2F(x) __builtin_amdgcn_exp2f(x)
#else
#define EXP2F(x) __builtin_exp2f(x)
#endif

// fast f32 -> bf16 (round-half-up) packed pair via v_perm_b32
__device__ __forceinline__ u32 pk_bf16(float lo, float hi) {
  u32 a = __float_as_uint(lo) + 0x8000u;
  u32 b = __float_as_uint(hi) + 0x8000u;
  return __builtin_amdgcn_perm(b, a, 0x07060302);  // [bf16(lo) | bf16(hi)<<16]
}
__device__ __forceinline__ unsigned short bf16r(float x) {
  return (unsigned short)((__float_as_uint(x) + 0x8000u) >> 16);
}

// async global->LDS, 16B per lane. LDS dest = wave-uniform base + lane*16.
__device__ __forceinline__ void async_ld16(void* lds, const void* g) {
  __builtin_amdgcn_global_load_lds(
      (const __attribute__((address_space(1))) void*)(g),
      (__attribute__((address_space(3))) void*)(lds),
      16, 0, 0);
}

// ---------------------------------------------------------------------------
// x (fp32) -> xb (bf16), 4 elems/thread
// ---------------------------------------------------------------------------
__global__ void convert_x(const float* __restrict__ x, bf16* __restrict__ xb) {
  int i = blockIdx.x * 256 + threadIdx.x;
  float4 v = ((const float4*)x)[i];
  u32x2 o = { pk_bf16(v.x, v.y), pk_bf16(v.z, v.w) };
  *(u32x2*)(xb + (size_t)i * 4) = o;
}

// ---------------------------------------------------------------------------
// Prep: WT_perm[n'][k] = (bf16)W_qkv[k][orig_n(n')], n' = which*1024+h*64+d,
// orig_n = d*48 + which*16 + h.  (folds the (d,k,h) deinterleave + fp32->bf16)
// ---------------------------------------------------------------------------
__global__ void prep_wqkv(const float* __restrict__ W, bf16* __restrict__ WT) {
  __shared__ float s[4 * 3072];             // 48 KB
  const int k0 = blockIdx.x * 4;            // 256 blocks
  for (int i = threadIdx.x; i < 3072; i += 256) {   // 4 rows * 768 float4
    int r = i / 768, c = (i - r * 768) * 4;
    *(float4*)(s + r * 3072 + c) = *(const float4*)(W + (size_t)(k0 + r) * 3072 + c);
  }
  __syncthreads();
  for (int n = threadIdx.x; n < 3072; n += 256) {
    int d = n & 63, h = (n >> 6) & 15, wch = n >> 10;
    int on = d * 48 + wch * 16 + h;
    u32x2 v = { pk_bf16(s[0 * 3072 + on], s[1 * 3072 + on]),
                pk_bf16(s[2 * 3072 + on], s[3 * 3072 + on]) };
    *(u32x2*)(WT + (size_t)n * 1024 + k0) = v;
  }
}

// WoT[n][k] = (bf16)W_o[k][n]
__global__ void prep_wo(const float* __restrict__ W, bf16* __restrict__ WT) {
  __shared__ float s[8 * 1024];             // 32 KB
  const int k0 = blockIdx.x * 8;            // 128 blocks
  for (int i = threadIdx.x; i < 2048; i += 256) {   // 8 rows * 256 float4
    int r = i >> 8, c = (i & 255) * 4;
    *(float4*)(s + r * 1024 + c) = *(const float4*)(W + (size_t)(k0 + r) * 1024 + c);
  }
  __syncthreads();
  for (int n = threadIdx.x; n < 1024; n += 256) {
    u32x4 v = { pk_bf16(s[0 * 1024 + n], s[1 * 1024 + n]),
                pk_bf16(s[2 * 1024 + n], s[3 * 1024 + n]),
                pk_bf16(s[4 * 1024 + n], s[5 * 1024 + n]),
                pk_bf16(s[6 * 1024 + n], s[7 * 1024 + n]) };
    *(u32x4*)(WT + (size_t)n * 1024 + k0) = v;
  }
}

// ---------------------------------------------------------------------------
// GEMM: C = A[M][1024] * BT[N][1024]^T, 128x128 tile, BK=32, 4 waves.
// MODE 0: write C natural as fp32.  MODE 1: scatter bf16 into Q/K/V [b,h,t,d]
// (cols already permuted to which|h|d order so stores are 32B-coalesced).
// Q columns (wch==0) are pre-scaled by EXP_SC for the attention exp2.
// ---------------------------------------------------------------------------
template <int MODE>
__launch_bounds__(256, 2)
__global__ void gemm_bt(const bf16* __restrict__ A, const bf16* __restrict__ BT,
                        float* __restrict__ C, int N,
                        bf16* __restrict__ Qb, bf16* __restrict__ Kb, bf16* __restrict__ Vb) {
  constexpr int K = 1024;
  __shared__ bf16 sA[128 * 32];             // 8 KB
  __shared__ bf16 sB[128 * 32];             // 8 KB
  const int m0 = blockIdx.y * 128;
  const int n0 = blockIdx.x * 128;
  const int tid = threadIdx.x;
  const int lane = tid & 63;
  const int w = tid >> 6;
  const int wm = (w >> 1) * 64, wn = (w & 1) * 64;
  const int l15 = lane & 15, quad = lane >> 4;

  f32x4 acc[4][4];
  for (int i = 0; i < 4; i++)
    for (int j = 0; j < 4; j++) acc[i][j] = f32x4{0.f, 0.f, 0.f, 0.f};

  const int c0 = w * 128 + lane;            // 16B-chunk ids, 512/tile
  const int c1 = c0 + 64;
  const int r0 = c0 >> 2, jg0 = (c0 & 3) ^ (r0 & 3);
  const int r1 = c1 >> 2, jg1 = (c1 & 3) ^ (r1 & 3);

  const bf16* gA0 = A  + (size_t)(m0 + r0) * K + jg0 * 8;
  const bf16* gA1 = A  + (size_t)(m0 + r1) * K + jg1 * 8;
  const bf16* gB0 = BT + (size_t)(n0 + r0) * K + jg0 * 8;
  const bf16* gB1 = BT + (size_t)(n0 + r1) * K + jg1 * 8;

  for (int k0 = 0; k0 < K; k0 += 32) {
    __syncthreads();
    // XOR-swizzled (row&3) 16B chunks to kill ds_read_b128 conflicts
    async_ld16((void*)(sA + (w * 2) * 512),     gA0);
    async_ld16((void*)(sA + (w * 2 + 1) * 512), gA1);
    async_ld16((void*)(sB + (w * 2) * 512),     gB0);
    async_ld16((void*)(sB + (w * 2 + 1) * 512), gB1);
    gA0 += 32; gA1 += 32; gB0 += 32; gB1 += 32;
    __syncthreads();

    bf16x8 af[4], bfr[4];
    for (int ms = 0; ms < 4; ms++) {
      int r = wm + ms * 16 + l15;
      af[ms] = *(const bf16x8*)(sA + r * 32 + ((quad ^ (r & 3)) * 8));
    }
    for (int ns = 0; ns < 4; ns++) {
      int r = wn + ns * 16 + l15;
      bfr[ns] = *(const bf16x8*)(sB + r * 32 + ((quad ^ (r & 3)) * 8));
    }
    for (int ms = 0; ms < 4; ms++)
      for (int ns = 0; ns < 4; ns++)
        acc[ms][ns] = __builtin_amdgcn_mfma_f32_16x16x32_bf16(af[ms], bfr[ns], acc[ms][ns], 0, 0, 0);
  }

  if (MODE == 0) {
    for (int ms = 0; ms < 4; ms++)
      for (int ns = 0; ns < 4; ns++)
        for (int r = 0; r < 4; r++) {
          int row = m0 + wm + ms * 16 + quad * 4 + r;
          int col = n0 + wn + ns * 16 + l15;
          C[(size_t)row * N + col] = acc[ms][ns][r];
        }
  } else {
    for (int ms = 0; ms < 4; ms++)
      for (int ns = 0; ns < 4; ns++)
        for (int r = 0; r < 4; r++) {
          int row = m0 + wm + ms * 16 + quad * 4 + r;
          int col = n0 + wn + ns * 16 + l15;
          int b = row >> 11, t = row & 2047;
          int d = col & 63, h = (col >> 6) & 15, wch = col >> 10;
          bf16* dst = (wch == 0) ? Qb : (wch == 1) ? Kb : Vb;
          float v = acc[ms][ns][r] * ((wch == 0) ? EXP_SC : 1.0f);
          ((unsigned short*)dst)[(((size_t)(b * 16 + h)) * 2048 + t) * 64 + d] = bf16r(v);
        }
  }
}

// ---------------------------------------------------------------------------
// V [bh][t][d] -> VTp [bh][d][t'] with keys PERMUTED within each 64-tile:
// VTp[d][kt + k'] = V[kt + invpi(k')][d], invpi(k') = (k'&3)*16 + (k'>>2).
// (matches attn_fwd's packed-P column order pi(c) = (c&15)*4 + (c>>4))
// ---------------------------------------------------------------------------
__global__ void transpose_v(const bf16* __restrict__ V, bf16* __restrict__ VT) {
  __shared__ bf16 s[64 * 66];
  const int bh = blockIdx.y;
  const int t0 = blockIdx.x * 64;
  for (int i = threadIdx.x; i < 512; i += 256) {
    int t = i >> 3, dc = (i & 7) * 8;
    bf16x8 v = *(const bf16x8*)(V + ((size_t)bh * 2048 + t0 + t) * 64 + dc);
    for (int j = 0; j < 8; j++) s[t * 66 + dc + j] = v[j];
  }
  __syncthreads();
  for (int i = threadIdx.x; i < 512; i += 256) {
    int d = i >> 3, tc = (i & 7) * 8;
    bf16x8 v;
    for (int j = 0; j < 8; j++) {
      int kp = tc + j;
      int src = ((kp & 3) * 16) + (kp >> 2);      // invpi
      v[j] = s[src * 66 + d];
    }
    *(bf16x8*)(VT + ((size_t)bh * 64 + d) * 2048 + t0 + tc) = v;
  }
}

// ---------------------------------------------------------------------------
// Flash attention, shift-free softmax (Q pre-scaled by 0.125*log2(e)):
// p = exp2(qk); l = P*ones via MFMA. P packed via v_perm, key-permuted.
// DOUBLE-BUFFERED K/V staging with ONE barrier per tile: the prefetch for
// tile i+1 is issued right after the barrier and has the whole compute
// phase of tile i to complete (the barrier's vmcnt-drain then costs ~0).
// Block = 128 queries of one bh, 4 waves x 32 queries, KTILE=64.
// ---------------------------------------------------------------------------
__launch_bounds__(256, 2)
__global__ void attn_fwd(const bf16* __restrict__ Q, const bf16* __restrict__ K,
                         const bf16* __restrict__ VT, bf16* __restrict__ O) {
  __shared__ bf16 sK[2][64 * 64];           // 16 KB [key][d]  (chunk-swizzled)
  __shared__ bf16 sV[2][64 * 64];           // 16 KB [d][key'] (key-permuted)
  __shared__ bf16 sP[4][32 * 64];           // 16 KB per-wave P buffers
  const int bh = blockIdx.y;
  const int q0 = blockIdx.x * 128;
  const int tid = threadIdx.x;
  const int lane = tid & 63, w = tid >> 6;
  const int l15 = lane & 15, quad = lane >> 4;

  bf16x8 qf[2][2];
  for (int ms = 0; ms < 2; ms++)
    for (int kk = 0; kk < 2; kk++)
      qf[ms][kk] = *(const bf16x8*)(Q + ((size_t)bh * 2048 + q0 + w * 32 + ms * 16 + l15) * 64 + kk * 32 + quad * 8);

  f32x4 oa[2][4], lacc[2];
  for (int ms = 0; ms < 2; ms++) {
    for (int ds = 0; ds < 4; ds++) oa[ms][ds] = f32x4{0.f, 0.f, 0.f, 0.f};
    lacc[ms] = f32x4{0.f, 0.f, 0.f, 0.f};
  }
  bf16x8 onesf;
  for (int i = 0; i < 8; i++) onesf[i] = (bf16)1.0f;

  // staging pointers (advance by constants each tile)
  const int cA = w * 128 + lane;            // 512 16B chunks per 64x64 tile
  const int cB = cA + 64;
  const int rA = cA >> 3, jA = (cA & 7) ^ (rA & 7);
  const int rB = cB >> 3, jB = (cB & 7) ^ (rB & 7);
  const bf16* gKA = K  + ((size_t)bh * 2048 + rA) * 64 + jA * 8;
  const bf16* gKB = K  + ((size_t)bh * 2048 + rB) * 64 + jB * 8;
  const bf16* gVA = VT + ((size_t)bh * 64 + rA) * 2048 + jA * 8;
  const bf16* gVB = VT + ((size_t)bh * 64 + rB) * 2048 + jB * 8;

  // loop-invariant LDS fragment offsets
  int kvo[4][2], pfo[2][2], pwo[2][4];
  for (int ns = 0; ns < 4; ns++)
    for (int kk = 0; kk < 2; kk++) {
      int r = ns * 16 + l15;
      kvo[ns][kk] = r * 64 + (((kk * 4 + quad) ^ (r & 7)) * 8);
    }
  for (int ms = 0; ms < 2; ms++) {
    int r = ms * 16 + l15;
    for (int kk = 0; kk < 2; kk++)
      pfo[ms][kk] = r * 64 + (((kk * 4 + quad) ^ (r & 7)) * 8);
    for (int rr = 0; rr < 4; rr++) {
      int row = ms * 16 + quad * 4 + rr;
      pwo[ms][rr] = row * 64 + (((l15 >> 1) ^ (row & 7)) * 8) + (l15 & 1) * 4;
    }
  }

  // prologue: stage tile 0 into buffer 0
  async_ld16((void*)(sK[0] + w * 1024),       gKA);
  async_ld16((void*)(sV[0] + w * 1024),       gVA);
  async_ld16((void*)(sK[0] + w * 1024 + 512), gKB);
  async_ld16((void*)(sV[0] + w * 1024 + 512), gVB);
  gKA += 4096; gKB += 4096; gVA += 64; gVB += 64;

  int buf = 0;
  for (int it = 0; it < 32; it++) {
    __syncthreads();   // current buf landed; other buf's readers all done
    if (it < 31) {     // prefetch next tile into the other buffer
      int nb = buf ^ 1;
      async_ld16((void*)(sK[nb] + w * 1024),       gKA);
      async_ld16((void*)(sV[nb] + w * 1024),       gVA);
      async_ld16((void*)(sK[nb] + w * 1024 + 512), gKB);
      async_ld16((void*)(sV[nb] + w * 1024 + 512), gVB);
      gKA += 4096; gKB += 4096; gVA += 64; gVB += 64;
    }
    const bf16* sKc = sK[buf];
    const bf16* sVc = sV[buf];

    // S = Q K^T (scale pre-folded into Q)
    bf16x8 kf[4][2];
    for (int ns = 0; ns < 4; ns++)
      for (int kk = 0; kk < 2; kk++)
        kf[ns][kk] = *(const bf16x8*)(sKc + kvo[ns][kk]);
    for (int ms = 0; ms < 2; ms++) {
      f32x4 s[4];
      for (int ns = 0; ns < 4; ns++) {
        f32x4 t = f32x4{0.f, 0.f, 0.f, 0.f};
        t = __builtin_amdgcn_mfma_f32_16x16x32_bf16(qf[ms][0], kf[ns][0], t, 0, 0, 0);
        t = __builtin_amdgcn_mfma_f32_16x16x32_bf16(qf[ms][1], kf[ns][1], t, 0, 0, 0);
        s[ns] = t;
      }
      // p = exp2(s); pack 4 cols -> one b64 store (storage col' = l15*4+ns)
      for (int r = 0; r < 4; r++) {
        u32x2 pk = { pk_bf16(EXP2F(s[0][r]), EXP2F(s[1][r])),
                     pk_bf16(EXP2F(s[2][r]), EXP2F(s[3][r])) };
        *(u32x2*)(sP[w] + pwo[ms][r]) = pk;
      }
    }

    // O += P V ; l += P * ones   (both in permuted key order)
    bf16x8 vf[4][2];
    for (int ds = 0; ds < 4; ds++)
      for (int kk = 0; kk < 2; kk++)
        vf[ds][kk] = *(const bf16x8*)(sVc + kvo[ds][kk]);
    for (int ms = 0; ms < 2; ms++) {
      bf16x8 pf0 = *(const bf16x8*)(sP[w] + pfo[ms][0]);
      bf16x8 pf1 = *(const bf16x8*)(sP[w] + pfo[ms][1]);
      lacc[ms] = __builtin_amdgcn_mfma_f32_16x16x32_bf16(pf0, onesf, lacc[ms], 0, 0, 0);
      lacc[ms] = __builtin_amdgcn_mfma_f32_16x16x32_bf16(pf1, onesf, lacc[ms], 0, 0, 0);
      for (int ds = 0; ds < 4; ds++) {
        oa[ms][ds] = __builtin_amdgcn_mfma_f32_16x16x32_bf16(pf0, vf[ds][0], oa[ms][ds], 0, 0, 0);
        oa[ms][ds] = __builtin_amdgcn_mfma_f32_16x16x32_bf16(pf1, vf[ds][1], oa[ms][ds], 0, 0, 0);
      }
    }
    buf ^= 1;
  }

  const int b = bh >> 4, h = bh & 15;
  for (int ms = 0; ms < 2; ms++)
    for (int r = 0; r < 4; r++) {
      float inv = 1.0f / lacc[ms][r];       // D[row][col]=l[row] in every col
      int t = q0 + w * 32 + ms * 16 + quad * 4 + r;
      for (int ds = 0; ds < 4; ds++)
        ((unsigned short*)O)[((size_t)b * 2048 + t) * 1024 + h * 64 + ds * 16 + l15] =
            bf16r(oa[ms][ds][r] * inv);
    }
}

// ---------------------------------------------------------------------------
extern "C" void kernel_launch(void* const* d_in, const int* in_sizes, int n_in,
                              void* d_out, int out_size, void* d_ws, size_t ws_size,
                              hipStream_t stream) {
  const float* x    = (const float*)d_in[0];   // [4,2048,1024] fp32
  const float* Wqkv = (const float*)d_in[1];   // [1024,3072] fp32
  const float* Wo   = (const float*)d_in[2];   // [1024,1024] fp32
  float* out = (float*)d_out;                  // [4,2048,1024] fp32
  char* ws = (char*)d_ws;

  bf16* wqkvT = (bf16*)(ws);                        //  6 MB [3072][1024] permuted bf16
  bf16* woT   = (bf16*)(ws + 6291456);              //  2 MB [1024][1024] bf16
  bf16* xb    = (bf16*)(ws + 8388608);              // 16 MB [8192][1024] bf16
  bf16* Qb    = (bf16*)(ws + 25165824);             // 16 MB [bh][t][d]
  bf16* Kb    = (bf16*)(ws + 41943040);             // 16 MB [bh][t][d]
  bf16* Vb    = (bf16*)(ws + 58720256);             // 16 MB [bh][t][d]
  bf16* VTb   = xb;   // x dead after QKV GEMM; reuse as V-transpose
  bf16* AOb   = Vb;   // V dead after transpose_v; reuse as attention output

  convert_x<<<8192, 256, 0, stream>>>(x, xb);
  prep_wqkv<<<256, 256, 0, stream>>>(Wqkv, wqkvT);
  prep_wo<<<128, 256, 0, stream>>>(Wo, woT);
  gemm_bt<1><<<dim3(24, 64), 256, 0, stream>>>(xb, wqkvT, nullptr, 3072, Qb, Kb, Vb);
  transpose_v<<<dim3(32, 64), 256, 0, stream>>>(Vb, VTb);
  attn_fwd<<<dim3(16, 64), 256, 0, stream>>>(Qb, Kb, VTb, AOb);
  gemm_bt<0><<<dim3(8, 64), 256, 0, stream>>>(AOb, woT, out, 1024, nullptr, nullptr, nullptr);
}

// Round 6
// 292.060 us; speedup vs baseline: 1.0180x; 1.0180x over previous
//
#include <hip/hip_runtime.h>

typedef __bf16 bf16;
typedef __bf16 bf16x2 __attribute__((ext_vector_type(2)));
typedef __bf16 bf16x4 __attribute__((ext_vector_type(4)));
typedef __bf16 bf16x8 __attribute__((ext_vector_type(8)));
typedef float  f32x4  __attribute__((ext_vector_type(4)));
typedef unsigned int u32;
typedef unsigned int u32x2 __attribute__((ext_vector_type(2)));
typedef unsigned int u32x4 __attribute__((ext_vector_type(4)));

#define LOG2E 1.44269504088896340736f
#define EXP_SC (0.125f * LOG2E)   // folded into Q at the QKV-GEMM epilogue

#if __has_builtin(__builtin_amdgcn_exp2f)
#define EXP2F(x) __builtin_amdgcn_exp2f(x)
#else
#define EXP2F(x) __builtin_exp2f(x)
#endif

// fast f32 -> bf16 (round-half-up) packed pair via v_perm_b32
__device__ __forceinline__ u32 pk_bf16(float lo, float hi) {
  u32 a = __float_as_uint(lo) + 0x8000u;
  u32 b = __float_as_uint(hi) + 0x8000u;
  return __builtin_amdgcn_perm(b, a, 0x07060302);  // [bf16(lo) | bf16(hi)<<16]
}
// packed pair via gfx950 v_cvt_pk_bf16_f32 when available (1 instr, RNE)
#if __has_builtin(__builtin_amdgcn_cvt_pk_bf16_f32)
__device__ __forceinline__ u32 cvtpk(float lo, float hi) {
  bf16x2 t = __builtin_amdgcn_cvt_pk_bf16_f32(lo, hi);
  return __builtin_bit_cast(u32, t);
}
#else
__device__ __forceinline__ u32 cvtpk(float lo, float hi) { return pk_bf16(lo, hi); }
#endif
__device__ __forceinline__ unsigned short bf16r(float x) {
  return (unsigned short)((__float_as_uint(x) + 0x8000u) >> 16);
}

// async global->LDS, 16B per lane. LDS dest = wave-uniform base + lane*16.
__device__ __forceinline__ void async_ld16(void* lds, const void* g) {
  __builtin_amdgcn_global_load_lds(
      (const __attribute__((address_space(1))) void*)(g),
      (__attribute__((address_space(3))) void*)(lds),
      16, 0, 0);
}

// ---------------------------------------------------------------------------
// x (fp32) -> xb (bf16), 4 elems/thread
// ---------------------------------------------------------------------------
__global__ void convert_x(const float* __restrict__ x, bf16* __restrict__ xb) {
  int i = blockIdx.x * 256 + threadIdx.x;
  float4 v = ((const float4*)x)[i];
  u32x2 o = { pk_bf16(v.x, v.y), pk_bf16(v.z, v.w) };
  *(u32x2*)(xb + (size_t)i * 4) = o;
}

// ---------------------------------------------------------------------------
// Prep: WT_perm[n'][k] = (bf16)W_qkv[k][orig_n(n')], n' = which*1024+h*64+d,
// orig_n = d*48 + which*16 + h.  (folds the (d,k,h) deinterleave + fp32->bf16)
// ---------------------------------------------------------------------------
__global__ void prep_wqkv(const float* __restrict__ W, bf16* __restrict__ WT) {
  __shared__ float s[4 * 3072];             // 48 KB
  const int k0 = blockIdx.x * 4;            // 256 blocks
  for (int i = threadIdx.x; i < 3072; i += 256) {   // 4 rows * 768 float4
    int r = i / 768, c = (i - r * 768) * 4;
    *(float4*)(s + r * 3072 + c) = *(const float4*)(W + (size_t)(k0 + r) * 3072 + c);
  }
  __syncthreads();
  for (int n = threadIdx.x; n < 3072; n += 256) {
    int d = n & 63, h = (n >> 6) & 15, wch = n >> 10;
    int on = d * 48 + wch * 16 + h;
    u32x2 v = { pk_bf16(s[0 * 3072 + on], s[1 * 3072 + on]),
                pk_bf16(s[2 * 3072 + on], s[3 * 3072 + on]) };
    *(u32x2*)(WT + (size_t)n * 1024 + k0) = v;
  }
}

// WoT[n][k] = (bf16)W_o[k][n]
__global__ void prep_wo(const float* __restrict__ W, bf16* __restrict__ WT) {
  __shared__ float s[8 * 1024];             // 32 KB
  const int k0 = blockIdx.x * 8;            // 128 blocks
  for (int i = threadIdx.x; i < 2048; i += 256) {   // 8 rows * 256 float4
    int r = i >> 8, c = (i & 255) * 4;
    *(float4*)(s + r * 1024 + c) = *(const float4*)(W + (size_t)(k0 + r) * 1024 + c);
  }
  __syncthreads();
  for (int n = threadIdx.x; n < 1024; n += 256) {
    u32x4 v = { pk_bf16(s[0 * 1024 + n], s[1 * 1024 + n]),
                pk_bf16(s[2 * 1024 + n], s[3 * 1024 + n]),
                pk_bf16(s[4 * 1024 + n], s[5 * 1024 + n]),
                pk_bf16(s[6 * 1024 + n], s[7 * 1024 + n]) };
    *(u32x4*)(WT + (size_t)n * 1024 + k0) = v;
  }
}

// ---------------------------------------------------------------------------
// GEMM: C = A[M][1024] * BT[N][1024]^T, 128x128 tile, BK=32, 4 waves.
// MODE 0: write C natural as fp32.  MODE 1: scatter bf16 into Q/K/V [b,h,t,d]
// (cols already permuted to which|h|d order so stores are 32B-coalesced).
// Q columns (wch==0) are pre-scaled by EXP_SC for the attention exp2.
// ---------------------------------------------------------------------------
template <int MODE>
__launch_bounds__(256, 2)
__global__ void gemm_bt(const bf16* __restrict__ A, const bf16* __restrict__ BT,
                        float* __restrict__ C, int N,
                        bf16* __restrict__ Qb, bf16* __restrict__ Kb, bf16* __restrict__ Vb) {
  constexpr int K = 1024;
  __shared__ bf16 sA[128 * 32];             // 8 KB
  __shared__ bf16 sB[128 * 32];             // 8 KB
  const int m0 = blockIdx.y * 128;
  const int n0 = blockIdx.x * 128;
  const int tid = threadIdx.x;
  const int lane = tid & 63;
  const int w = tid >> 6;
  const int wm = (w >> 1) * 64, wn = (w & 1) * 64;
  const int l15 = lane & 15, quad = lane >> 4;

  f32x4 acc[4][4];
  for (int i = 0; i < 4; i++)
    for (int j = 0; j < 4; j++) acc[i][j] = f32x4{0.f, 0.f, 0.f, 0.f};

  const int c0 = w * 128 + lane;            // 16B-chunk ids, 512/tile
  const int c1 = c0 + 64;
  const int r0 = c0 >> 2, jg0 = (c0 & 3) ^ (r0 & 3);
  const int r1 = c1 >> 2, jg1 = (c1 & 3) ^ (r1 & 3);

  const bf16* gA0 = A  + (size_t)(m0 + r0) * K + jg0 * 8;
  const bf16* gA1 = A  + (size_t)(m0 + r1) * K + jg1 * 8;
  const bf16* gB0 = BT + (size_t)(n0 + r0) * K + jg0 * 8;
  const bf16* gB1 = BT + (size_t)(n0 + r1) * K + jg1 * 8;

  for (int k0 = 0; k0 < K; k0 += 32) {
    __syncthreads();
    // XOR-swizzled (row&3) 16B chunks to kill ds_read_b128 conflicts
    async_ld16((void*)(sA + (w * 2) * 512),     gA0);
    async_ld16((void*)(sA + (w * 2 + 1) * 512), gA1);
    async_ld16((void*)(sB + (w * 2) * 512),     gB0);
    async_ld16((void*)(sB + (w * 2 + 1) * 512), gB1);
    gA0 += 32; gA1 += 32; gB0 += 32; gB1 += 32;
    __syncthreads();

    bf16x8 af[4], bfr[4];
    for (int ms = 0; ms < 4; ms++) {
      int r = wm + ms * 16 + l15;
      af[ms] = *(const bf16x8*)(sA + r * 32 + ((quad ^ (r & 3)) * 8));
    }
    for (int ns = 0; ns < 4; ns++) {
      int r = wn + ns * 16 + l15;
      bfr[ns] = *(const bf16x8*)(sB + r * 32 + ((quad ^ (r & 3)) * 8));
    }
    for (int ms = 0; ms < 4; ms++)
      for (int ns = 0; ns < 4; ns++)
        acc[ms][ns] = __builtin_amdgcn_mfma_f32_16x16x32_bf16(af[ms], bfr[ns], acc[ms][ns], 0, 0, 0);
  }

  if (MODE == 0) {
    for (int ms = 0; ms < 4; ms++)
      for (int ns = 0; ns < 4; ns++)
        for (int r = 0; r < 4; r++) {
          int row = m0 + wm + ms * 16 + quad * 4 + r;
          int col = n0 + wn + ns * 16 + l15;
          C[(size_t)row * N + col] = acc[ms][ns][r];
        }
  } else {
    for (int ms = 0; ms < 4; ms++)
      for (int ns = 0; ns < 4; ns++)
        for (int r = 0; r < 4; r++) {
          int row = m0 + wm + ms * 16 + quad * 4 + r;
          int col = n0 + wn + ns * 16 + l15;
          int b = row >> 11, t = row & 2047;
          int d = col & 63, h = (col >> 6) & 15, wch = col >> 10;
          bf16* dst = (wch == 0) ? Qb : (wch == 1) ? Kb : Vb;
          float v = acc[ms][ns][r] * ((wch == 0) ? EXP_SC : 1.0f);
          ((unsigned short*)dst)[(((size_t)(b * 16 + h)) * 2048 + t) * 64 + d] = bf16r(v);
        }
  }
}

// ---------------------------------------------------------------------------
// V [bh][t][d] -> VTp [bh][d][t'] with keys PERMUTED within each 64-tile:
// VTp[d][kt + k'] = V[kt + invpi(k')][d], invpi(k') = (k'&3)*16 + (k'>>2).
// (matches attn_fwd's packed-P column order pi(c) = (c&15)*4 + (c>>4))
// ---------------------------------------------------------------------------
__global__ void transpose_v(const bf16* __restrict__ V, bf16* __restrict__ VT) {
  __shared__ bf16 s[64 * 66];
  const int bh = blockIdx.y;
  const int t0 = blockIdx.x * 64;
  for (int i = threadIdx.x; i < 512; i += 256) {
    int t = i >> 3, dc = (i & 7) * 8;
    bf16x8 v = *(const bf16x8*)(V + ((size_t)bh * 2048 + t0 + t) * 64 + dc);
    for (int j = 0; j < 8; j++) s[t * 66 + dc + j] = v[j];
  }
  __syncthreads();
  for (int i = threadIdx.x; i < 512; i += 256) {
    int d = i >> 3, tc = (i & 7) * 8;
    bf16x8 v;
    for (int j = 0; j < 8; j++) {
      int kp = tc + j;
      int src = ((kp & 3) * 16) + (kp >> 2);      // invpi
      v[j] = s[src * 66 + d];
    }
    *(bf16x8*)(VT + ((size_t)bh * 64 + d) * 2048 + t0 + tc) = v;
  }
}

// ---------------------------------------------------------------------------
// Flash attention, shift-free softmax (Q pre-scaled by 0.125*log2(e)):
// p = exp2(qk); l = P*ones via MFMA. P packed via cvt_pk, key-permuted.
// 8 waves x 32 queries = 256 queries/block; KTILE=128 staged per barrier
// pair, computed as 2 x 64-key sub-tiles. LDS 64 KB -> 2 blocks/CU x 16
// waves: more independent wave groups to anti-phase VALU vs MFMA.
// ---------------------------------------------------------------------------
__launch_bounds__(512, 4)
__global__ void attn_fwd(const bf16* __restrict__ Q, const bf16* __restrict__ K,
                         const bf16* __restrict__ VT, bf16* __restrict__ O) {
  __shared__ bf16 sK[2 * 64 * 64];          // 16 KB [ht][key][d]  (swizzled)
  __shared__ bf16 sV[2 * 64 * 64];          // 16 KB [ht][d][key'] (key-permuted)
  __shared__ bf16 sP[8][32 * 64];           // 32 KB per-wave P buffers
  const int bh = blockIdx.y;
  const int q0 = blockIdx.x * 256;
  const int tid = threadIdx.x;              // 0..511
  const int lane = tid & 63, w = tid >> 6;  // 8 waves
  const int l15 = lane & 15, quad = lane >> 4;

  bf16x8 qf[2][2];
  for (int ms = 0; ms < 2; ms++)
    for (int kk = 0; kk < 2; kk++)
      qf[ms][kk] = *(const bf16x8*)(Q + ((size_t)bh * 2048 + q0 + w * 32 + ms * 16 + l15) * 64 + kk * 32 + quad * 8);

  f32x4 oa[2][4], lacc[2];
  for (int ms = 0; ms < 2; ms++) {
    for (int ds = 0; ds < 4; ds++) oa[ms][ds] = f32x4{0.f, 0.f, 0.f, 0.f};
    lacc[ms] = f32x4{0.f, 0.f, 0.f, 0.f};
  }
  bf16x8 onesf;
  for (int i = 0; i < 8; i++) onesf[i] = (bf16)1.0f;

  // staging: 1024 16B chunks per K (and V) 128-key tile; round q in {0,1}
  // covers sub-tile ht=q; chunk c = q*512 + tid, LDS offset c*16B.
  const int rS = tid >> 3;                  // row within 64x64 sub-tile
  const int jS = (tid & 7) ^ (rS & 7);      // swizzled 16B chunk in row
  const bf16* gK = K  + ((size_t)bh * 2048 + rS) * 64 + jS * 8;   // +kt*64, +q*4096
  const bf16* gV = VT + ((size_t)bh * 64 + rS) * 2048 + jS * 8;   // +kt,    +q*64

  // loop-invariant LDS fragment offsets (within a 64x64 sub-tile)
  int kvo[4][2], pfo[2][2], pwo[2][4];
  for (int ns = 0; ns < 4; ns++)
    for (int kk = 0; kk < 2; kk++) {
      int r = ns * 16 + l15;
      kvo[ns][kk] = r * 64 + (((kk * 4 + quad) ^ (r & 7)) * 8);
    }
  for (int ms = 0; ms < 2; ms++) {
    int r = ms * 16 + l15;
    for (int kk = 0; kk < 2; kk++)
      pfo[ms][kk] = r * 64 + (((kk * 4 + quad) ^ (r & 7)) * 8);
    for (int rr = 0; rr < 4; rr++) {
      int row = ms * 16 + quad * 4 + rr;
      pwo[ms][rr] = row * 64 + (((l15 >> 1) ^ (row & 7)) * 8) + (l15 & 1) * 4;
    }
  }

  for (int kt = 0; kt < 2048; kt += 128) {
    __syncthreads();
    async_ld16((void*)(sK + (w * 64) * 8),         gK);
    async_ld16((void*)(sK + (512 + w * 64) * 8),   gK + 4096);
    async_ld16((void*)(sV + (w * 64) * 8),         gV);
    async_ld16((void*)(sV + (512 + w * 64) * 8),   gV + 64);
    gK += 8192; gV += 128;
    __syncthreads();

    for (int ht = 0; ht < 2; ht++) {
      const bf16* sKc = sK + ht * 4096;
      const bf16* sVc = sV + ht * 4096;

      // S = Q K^T (scale pre-folded into Q)
      bf16x8 kf[4][2];
      for (int ns = 0; ns < 4; ns++)
        for (int kk = 0; kk < 2; kk++)
          kf[ns][kk] = *(const bf16x8*)(sKc + kvo[ns][kk]);
      for (int ms = 0; ms < 2; ms++) {
        f32x4 s[4];
        for (int ns = 0; ns < 4; ns++) {
          f32x4 t = f32x4{0.f, 0.f, 0.f, 0.f};
          t = __builtin_amdgcn_mfma_f32_16x16x32_bf16(qf[ms][0], kf[ns][0], t, 0, 0, 0);
          t = __builtin_amdgcn_mfma_f32_16x16x32_bf16(qf[ms][1], kf[ns][1], t, 0, 0, 0);
          s[ns] = t;
        }
        // p = exp2(s); pack 4 cols -> one b64 store (storage col' = l15*4+ns)
        for (int r = 0; r < 4; r++) {
          u32x2 pk = { cvtpk(EXP2F(s[0][r]), EXP2F(s[1][r])),
                       cvtpk(EXP2F(s[2][r]), EXP2F(s[3][r])) };
          *(u32x2*)(sP[w] + pwo[ms][r]) = pk;
        }
      }

      // O += P V ; l += P * ones   (both in permuted key order)
      bf16x8 vf[4][2];
      for (int ds = 0; ds < 4; ds++)
        for (int kk = 0; kk < 2; kk++)
          vf[ds][kk] = *(const bf16x8*)(sVc + kvo[ds][kk]);
      for (int ms = 0; ms < 2; ms++) {
        bf16x8 pf0 = *(const bf16x8*)(sP[w] + pfo[ms][0]);
        bf16x8 pf1 = *(const bf16x8*)(sP[w] + pfo[ms][1]);
        lacc[ms] = __builtin_amdgcn_mfma_f32_16x16x32_bf16(pf0, onesf, lacc[ms], 0, 0, 0);
        lacc[ms] = __builtin_amdgcn_mfma_f32_16x16x32_bf16(pf1, onesf, lacc[ms], 0, 0, 0);
        for (int ds = 0; ds < 4; ds++) {
          oa[ms][ds] = __builtin_amdgcn_mfma_f32_16x16x32_bf16(pf0, vf[ds][0], oa[ms][ds], 0, 0, 0);
          oa[ms][ds] = __builtin_amdgcn_mfma_f32_16x16x32_bf16(pf1, vf[ds][1], oa[ms][ds], 0, 0, 0);
        }
      }
    }
  }

  const int b = bh >> 4, h = bh & 15;
  for (int ms = 0; ms < 2; ms++)
    for (int r = 0; r < 4; r++) {
      float inv = 1.0f / lacc[ms][r];       // D[row][col]=l[row] in every col
      int t = q0 + w * 32 + ms * 16 + quad * 4 + r;
      for (int ds = 0; ds < 4; ds++)
        ((unsigned short*)O)[((size_t)b * 2048 + t) * 1024 + h * 64 + ds * 16 + l15] =
            bf16r(oa[ms][ds][r] * inv);
    }
}

// ---------------------------------------------------------------------------
extern "C" void kernel_launch(void* const* d_in, const int* in_sizes, int n_in,
                              void* d_out, int out_size, void* d_ws, size_t ws_size,
                              hipStream_t stream) {
  const float* x    = (const float*)d_in[0];   // [4,2048,1024] fp32
  const float* Wqkv = (const float*)d_in[1];   // [1024,3072] fp32
  const float* Wo   = (const float*)d_in[2];   // [1024,1024] fp32
  float* out = (float*)d_out;                  // [4,2048,1024] fp32
  char* ws = (char*)d_ws;

  bf16* wqkvT = (bf16*)(ws);                        //  6 MB [3072][1024] permuted bf16
  bf16* woT   = (bf16*)(ws + 6291456);              //  2 MB [1024][1024] bf16
  bf16* xb    = (bf16*)(ws + 8388608);              // 16 MB [8192][1024] bf16
  bf16* Qb    = (bf16*)(ws + 25165824);             // 16 MB [bh][t][d]
  bf16* Kb    = (bf16*)(ws + 41943040);             // 16 MB [bh][t][d]
  bf16* Vb    = (bf16*)(ws + 58720256);             // 16 MB [bh][t][d]
  bf16* VTb   = xb;   // x dead after QKV GEMM; reuse as V-transpose
  bf16* AOb   = Vb;   // V dead after transpose_v; reuse as attention output

  convert_x<<<8192, 256, 0, stream>>>(x, xb);
  prep_wqkv<<<256, 256, 0, stream>>>(Wqkv, wqkvT);
  prep_wo<<<128, 256, 0, stream>>>(Wo, woT);
  gemm_bt<1><<<dim3(24, 64), 256, 0, stream>>>(xb, wqkvT, nullptr, 3072, Qb, Kb, Vb);
  transpose_v<<<dim3(32, 64), 256, 0, stream>>>(Vb, VTb);
  attn_fwd<<<dim3(8, 64), 512, 0, stream>>>(Qb, Kb, VTb, AOb);
  gemm_bt<0><<<dim3(8, 64), 256, 0, stream>>>(AOb, woT, out, 1024, nullptr, nullptr, nullptr);
}

// Round 7
// 268.718 us; speedup vs baseline: 1.1064x; 1.0869x over previous
//
#include <hip/hip_runtime.h>

typedef __bf16 bf16;
typedef __bf16 bf16x2 __attribute__((ext_vector_type(2)));
typedef __bf16 bf16x4 __attribute__((ext_vector_type(4)));
typedef __bf16 bf16x8 __attribute__((ext_vector_type(8)));
typedef float  f32x4  __attribute__((ext_vector_type(4)));
typedef unsigned int u32;
typedef unsigned int u32x2 __attribute__((ext_vector_type(2)));
typedef unsigned int u32x4 __attribute__((ext_vector_type(4)));

#define LOG2E 1.44269504088896340736f
#define EXP_SC (0.125f * LOG2E)   // folded into Q at the QKV-GEMM epilogue

#if __has_builtin(__builtin_amdgcn_exp2f)
#define EXP2F(x) __builtin_amdgcn_exp2f(x)
#else
#define EXP2F(x) __builtin_exp2f(x)
#endif

// fast f32 -> bf16 (round-half-up) packed pair via v_perm_b32
__device__ __forceinline__ u32 pk_bf16(float lo, float hi) {
  u32 a = __float_as_uint(lo) + 0x8000u;
  u32 b = __float_as_uint(hi) + 0x8000u;
  return __builtin_amdgcn_perm(b, a, 0x07060302);  // [bf16(lo) | bf16(hi)<<16]
}
// packed pair via gfx950 v_cvt_pk_bf16_f32 when available (1 instr, RNE)
#if __has_builtin(__builtin_amdgcn_cvt_pk_bf16_f32)
__device__ __forceinline__ u32 cvtpk(float lo, float hi) {
  bf16x2 t = __builtin_amdgcn_cvt_pk_bf16_f32(lo, hi);
  return __builtin_bit_cast(u32, t);
}
#else
__device__ __forceinline__ u32 cvtpk(float lo, float hi) { return pk_bf16(lo, hi); }
#endif
__device__ __forceinline__ unsigned short bf16r(float x) {
  return (unsigned short)((__float_as_uint(x) + 0x8000u) >> 16);
}

// async global->LDS, 16B per lane. LDS dest = wave-uniform base + lane*16.
__device__ __forceinline__ void async_ld16(void* lds, const void* g) {
  __builtin_amdgcn_global_load_lds(
      (const __attribute__((address_space(1))) void*)(g),
      (__attribute__((address_space(3))) void*)(lds),
      16, 0, 0);
}

// ---------------------------------------------------------------------------
// Fused prep: one launch, three block ranges (phases overlap across CUs).
//   [0, 8192)      : x fp32 -> xb bf16 (4 elems/thread)
//   [8192, 8448)   : WT_perm[n'][k] = bf16(W_qkv[k][orig_n(n')]),
//                    n' = which*1024+h*64+d, orig_n = d*48+which*16+h
//   [8448, 8576)   : WoT[n][k] = bf16(W_o[k][n])
// ---------------------------------------------------------------------------
__global__ void prep_all(const float* __restrict__ x,    bf16* __restrict__ xb,
                         const float* __restrict__ Wqkv, bf16* __restrict__ wqkvT,
                         const float* __restrict__ Wo,   bf16* __restrict__ woT) {
  __shared__ float s[12288];                // 48 KB
  const int bid = blockIdx.x;
  const int tid = threadIdx.x;
  if (bid < 8192) {
    int i = bid * 256 + tid;
    float4 v = ((const float4*)x)[i];
    u32x2 o = { pk_bf16(v.x, v.y), pk_bf16(v.z, v.w) };
    *(u32x2*)(xb + (size_t)i * 4) = o;
  } else if (bid < 8448) {
    const int k0 = (bid - 8192) * 4;
    for (int i = tid; i < 3072; i += 256) {       // 4 rows * 768 float4
      int r = i / 768, c = (i - r * 768) * 4;
      *(float4*)(s + r * 3072 + c) = *(const float4*)(Wqkv + (size_t)(k0 + r) * 3072 + c);
    }
    __syncthreads();
    for (int n = tid; n < 3072; n += 256) {
      int d = n & 63, h = (n >> 6) & 15, wch = n >> 10;
      int on = d * 48 + wch * 16 + h;
      u32x2 v = { pk_bf16(s[0 * 3072 + on], s[1 * 3072 + on]),
                  pk_bf16(s[2 * 3072 + on], s[3 * 3072 + on]) };
      *(u32x2*)(wqkvT + (size_t)n * 1024 + k0) = v;
    }
  } else {
    const int k0 = (bid - 8448) * 8;
    for (int i = tid; i < 2048; i += 256) {       // 8 rows * 256 float4
      int r = i >> 8, c = (i & 255) * 4;
      *(float4*)(s + r * 1024 + c) = *(const float4*)(Wo + (size_t)(k0 + r) * 1024 + c);
    }
    __syncthreads();
    for (int n = tid; n < 1024; n += 256) {
      u32x4 v = { pk_bf16(s[0 * 1024 + n], s[1 * 1024 + n]),
                  pk_bf16(s[2 * 1024 + n], s[3 * 1024 + n]),
                  pk_bf16(s[4 * 1024 + n], s[5 * 1024 + n]),
                  pk_bf16(s[6 * 1024 + n], s[7 * 1024 + n]) };
      *(u32x4*)(woT + (size_t)n * 1024 + k0) = v;
    }
  }
}

// ---------------------------------------------------------------------------
// GEMM: C = A[M][1024] * BT[N][1024]^T, 128x128 tile, BK=64, 4 waves.
// 32 MFMA per barrier pair (halved barrier count vs BK=32).
// Grid is (m-blocks, n-blocks): id%8 = m-block%8 -> A-tile L2 reuse per XCD.
// MODE 0: fp32 C.  MODE 1: scatter bf16 into Q/K/V [b,h,t,d]; Q pre-scaled.
// ---------------------------------------------------------------------------
template <int MODE>
__launch_bounds__(256, 2)
__global__ void gemm_bt(const bf16* __restrict__ A, const bf16* __restrict__ BT,
                        float* __restrict__ C, int N,
                        bf16* __restrict__ Qb, bf16* __restrict__ Kb, bf16* __restrict__ Vb) {
  constexpr int K = 1024;
  __shared__ bf16 sA[128 * 64];             // 16 KB
  __shared__ bf16 sB[128 * 64];             // 16 KB
  const int m0 = blockIdx.x * 128;
  const int n0 = blockIdx.y * 128;
  const int tid = threadIdx.x;
  const int lane = tid & 63;
  const int w = tid >> 6;
  const int wm = (w >> 1) * 64, wn = (w & 1) * 64;
  const int l15 = lane & 15, quad = lane >> 4;

  f32x4 acc[4][4];
  for (int i = 0; i < 4; i++)
    for (int j = 0; j < 4; j++) acc[i][j] = f32x4{0.f, 0.f, 0.f, 0.f};

  // staging: 1024 16B chunks per 128x64 tile; thread covers chunks tid+i*256.
  // chunk c -> row r=c>>3, col chunk j=(c&7)^(r&7) (XOR swizzle). Since
  // 256|i*256 and 32|i*32, r&7 and c&7 are i-invariant per thread.
  const int rT = tid >> 3;
  const int jT = (tid & 7) ^ (rT & 7);
  const bf16* gA = A  + (size_t)(m0 + rT) * K + jT * 8;
  const bf16* gB = BT + (size_t)(n0 + rT) * K + jT * 8;

  for (int k0 = 0; k0 < K; k0 += 64) {
    __syncthreads();
    for (int i = 0; i < 4; i++) {
      async_ld16((void*)(sA + (i * 256 + w * 64) * 8), gA + (size_t)i * 32 * K);
      async_ld16((void*)(sB + (i * 256 + w * 64) * 8), gB + (size_t)i * 32 * K);
    }
    gA += 64; gB += 64;
    __syncthreads();

    for (int kk = 0; kk < 2; kk++) {
      bf16x8 af[4], bfr[4];
      for (int ms = 0; ms < 4; ms++) {
        int r = wm + ms * 16 + l15;
        af[ms] = *(const bf16x8*)(sA + r * 64 + (((kk * 4 + quad) ^ (r & 7)) * 8));
      }
      for (int ns = 0; ns < 4; ns++) {
        int r = wn + ns * 16 + l15;
        bfr[ns] = *(const bf16x8*)(sB + r * 64 + (((kk * 4 + quad) ^ (r & 7)) * 8));
      }
      for (int ms = 0; ms < 4; ms++)
        for (int ns = 0; ns < 4; ns++)
          acc[ms][ns] = __builtin_amdgcn_mfma_f32_16x16x32_bf16(af[ms], bfr[ns], acc[ms][ns], 0, 0, 0);
    }
  }

  if (MODE == 0) {
    for (int ms = 0; ms < 4; ms++)
      for (int ns = 0; ns < 4; ns++)
        for (int r = 0; r < 4; r++) {
          int row = m0 + wm + ms * 16 + quad * 4 + r;
          int col = n0 + wn + ns * 16 + l15;
          C[(size_t)row * N + col] = acc[ms][ns][r];
        }
  } else {
    for (int ms = 0; ms < 4; ms++)
      for (int ns = 0; ns < 4; ns++)
        for (int r = 0; r < 4; r++) {
          int row = m0 + wm + ms * 16 + quad * 4 + r;
          int col = n0 + wn + ns * 16 + l15;
          int b = row >> 11, t = row & 2047;
          int d = col & 63, h = (col >> 6) & 15, wch = col >> 10;
          bf16* dst = (wch == 0) ? Qb : (wch == 1) ? Kb : Vb;
          float v = acc[ms][ns][r] * ((wch == 0) ? EXP_SC : 1.0f);
          ((unsigned short*)dst)[(((size_t)(b * 16 + h)) * 2048 + t) * 64 + d] = bf16r(v);
        }
  }
}

// ---------------------------------------------------------------------------
// V [bh][t][d] -> VTp [bh][d][t'] with keys PERMUTED within each 64-tile:
// VTp[d][kt + k'] = V[kt + invpi(k')][d], invpi(k') = (k'&3)*16 + (k'>>2).
// (matches attn_fwd's packed-P column order pi(c) = (c&15)*4 + (c>>4))
// ---------------------------------------------------------------------------
__global__ void transpose_v(const bf16* __restrict__ V, bf16* __restrict__ VT) {
  __shared__ bf16 s[64 * 66];
  const int bh = blockIdx.y;
  const int t0 = blockIdx.x * 64;
  for (int i = threadIdx.x; i < 512; i += 256) {
    int t = i >> 3, dc = (i & 7) * 8;
    bf16x8 v = *(const bf16x8*)(V + ((size_t)bh * 2048 + t0 + t) * 64 + dc);
    for (int j = 0; j < 8; j++) s[t * 66 + dc + j] = v[j];
  }
  __syncthreads();
  for (int i = threadIdx.x; i < 512; i += 256) {
    int d = i >> 3, tc = (i & 7) * 8;
    bf16x8 v;
    for (int j = 0; j < 8; j++) {
      int kp = tc + j;
      int src = ((kp & 3) * 16) + (kp >> 2);      // invpi
      v[j] = s[src * 66 + d];
    }
    *(bf16x8*)(VT + ((size_t)bh * 64 + d) * 2048 + t0 + tc) = v;
  }
}

// ---------------------------------------------------------------------------
// Flash attention (R4 structure: 4 waves x 32 queries, KTILE=64, 32 KB LDS,
// 2 barriers/tile). Shift-free softmax (Q pre-scaled), l = P*ones via MFMA,
// P packed via cvt_pk (key-permuted), V pre-permuted.
// GRID: blockIdx.x = bh, blockIdx.y = q-tile  ->  linear_id%8 == bh%8, so
// all 16 q-tiles of one bh share an XCD and K/V stay L2-resident.
// ---------------------------------------------------------------------------
__launch_bounds__(256, 2)
__global__ void attn_fwd(const bf16* __restrict__ Q, const bf16* __restrict__ K,
                         const bf16* __restrict__ VT, bf16* __restrict__ O) {
  __shared__ bf16 sK[64 * 64];              // 8 KB  [key][d]  (chunk-swizzled)
  __shared__ bf16 sV[64 * 64];              // 8 KB  [d][key'] (key-permuted)
  __shared__ bf16 sP[4][32 * 64];           // 16 KB per-wave P buffers
  const int bh = blockIdx.x;
  const int q0 = blockIdx.y * 128;
  const int tid = threadIdx.x;
  const int lane = tid & 63, w = tid >> 6;
  const int l15 = lane & 15, quad = lane >> 4;

  bf16x8 qf[2][2];
  for (int ms = 0; ms < 2; ms++)
    for (int kk = 0; kk < 2; kk++)
      qf[ms][kk] = *(const bf16x8*)(Q + ((size_t)bh * 2048 + q0 + w * 32 + ms * 16 + l15) * 64 + kk * 32 + quad * 8);

  f32x4 oa[2][4], lacc[2];
  for (int ms = 0; ms < 2; ms++) {
    for (int ds = 0; ds < 4; ds++) oa[ms][ds] = f32x4{0.f, 0.f, 0.f, 0.f};
    lacc[ms] = f32x4{0.f, 0.f, 0.f, 0.f};
  }
  bf16x8 onesf;
  for (int i = 0; i < 8; i++) onesf[i] = (bf16)1.0f;

  // staging pointers (advance by constants each tile)
  const int cA = w * 128 + lane;            // 512 16B chunks per 64x64 tile
  const int cB = cA + 64;
  const int rA = cA >> 3, jA = (cA & 7) ^ (rA & 7);
  const int rB = cB >> 3, jB = (cB & 7) ^ (rB & 7);
  const bf16* gKA = K  + ((size_t)bh * 2048 + rA) * 64 + jA * 8;
  const bf16* gKB = K  + ((size_t)bh * 2048 + rB) * 64 + jB * 8;
  const bf16* gVA = VT + ((size_t)bh * 64 + rA) * 2048 + jA * 8;
  const bf16* gVB = VT + ((size_t)bh * 64 + rB) * 2048 + jB * 8;

  // loop-invariant LDS fragment offsets
  int kvo[4][2], pfo[2][2], pwo[2][4];
  for (int ns = 0; ns < 4; ns++)
    for (int kk = 0; kk < 2; kk++) {
      int r = ns * 16 + l15;
      kvo[ns][kk] = r * 64 + (((kk * 4 + quad) ^ (r & 7)) * 8);
    }
  for (int ms = 0; ms < 2; ms++) {
    int r = ms * 16 + l15;
    for (int kk = 0; kk < 2; kk++)
      pfo[ms][kk] = r * 64 + (((kk * 4 + quad) ^ (r & 7)) * 8);
    for (int rr = 0; rr < 4; rr++) {
      int row = ms * 16 + quad * 4 + rr;
      pwo[ms][rr] = row * 64 + (((l15 >> 1) ^ (row & 7)) * 8) + (l15 & 1) * 4;
    }
  }

  for (int kt = 0; kt < 2048; kt += 64) {
    __syncthreads();
    async_ld16((void*)(sK + w * 1024),       gKA);
    async_ld16((void*)(sV + w * 1024),       gVA);
    async_ld16((void*)(sK + w * 1024 + 512), gKB);
    async_ld16((void*)(sV + w * 1024 + 512), gVB);
    gKA += 4096; gKB += 4096; gVA += 64; gVB += 64;
    __syncthreads();

    // S = Q K^T (scale pre-folded into Q)
    bf16x8 kf[4][2];
    for (int ns = 0; ns < 4; ns++)
      for (int kk = 0; kk < 2; kk++)
        kf[ns][kk] = *(const bf16x8*)(sK + kvo[ns][kk]);
    for (int ms = 0; ms < 2; ms++) {
      f32x4 s[4];
      for (int ns = 0; ns < 4; ns++) {
        f32x4 t = f32x4{0.f, 0.f, 0.f, 0.f};
        t = __builtin_amdgcn_mfma_f32_16x16x32_bf16(qf[ms][0], kf[ns][0], t, 0, 0, 0);
        t = __builtin_amdgcn_mfma_f32_16x16x32_bf16(qf[ms][1], kf[ns][1], t, 0, 0, 0);
        s[ns] = t;
      }
      // p = exp2(s); pack 4 cols -> one b64 store (storage col' = l15*4+ns)
      for (int r = 0; r < 4; r++) {
        u32x2 pk = { cvtpk(EXP2F(s[0][r]), EXP2F(s[1][r])),
                     cvtpk(EXP2F(s[2][r]), EXP2F(s[3][r])) };
        *(u32x2*)(sP[w] + pwo[ms][r]) = pk;
      }
    }

    // O += P V ; l += P * ones   (both in permuted key order)
    bf16x8 vf[4][2];
    for (int ds = 0; ds < 4; ds++)
      for (int kk = 0; kk < 2; kk++)
        vf[ds][kk] = *(const bf16x8*)(sV + kvo[ds][kk]);
    for (int ms = 0; ms < 2; ms++) {
      bf16x8 pf0 = *(const bf16x8*)(sP[w] + pfo[ms][0]);
      bf16x8 pf1 = *(const bf16x8*)(sP[w] + pfo[ms][1]);
      lacc[ms] = __builtin_amdgcn_mfma_f32_16x16x32_bf16(pf0, onesf, lacc[ms], 0, 0, 0);
      lacc[ms] = __builtin_amdgcn_mfma_f32_16x16x32_bf16(pf1, onesf, lacc[ms], 0, 0, 0);
      for (int ds = 0; ds < 4; ds++) {
        oa[ms][ds] = __builtin_amdgcn_mfma_f32_16x16x32_bf16(pf0, vf[ds][0], oa[ms][ds], 0, 0, 0);
        oa[ms][ds] = __builtin_amdgcn_mfma_f32_16x16x32_bf16(pf1, vf[ds][1], oa[ms][ds], 0, 0, 0);
      }
    }
  }

  const int b = bh >> 4, h = bh & 15;
  for (int ms = 0; ms < 2; ms++)
    for (int r = 0; r < 4; r++) {
      float inv = 1.0f / lacc[ms][r];       // D[row][col]=l[row] in every col
      int t = q0 + w * 32 + ms * 16 + quad * 4 + r;
      for (int ds = 0; ds < 4; ds++)
        ((unsigned short*)O)[((size_t)b * 2048 + t) * 1024 + h * 64 + ds * 16 + l15] =
            bf16r(oa[ms][ds][r] * inv);
    }
}

// ---------------------------------------------------------------------------
extern "C" void kernel_launch(void* const* d_in, const int* in_sizes, int n_in,
                              void* d_out, int out_size, void* d_ws, size_t ws_size,
                              hipStream_t stream) {
  const float* x    = (const float*)d_in[0];   // [4,2048,1024] fp32
  const float* Wqkv = (const float*)d_in[1];   // [1024,3072] fp32
  const float* Wo   = (const float*)d_in[2];   // [1024,1024] fp32
  float* out = (float*)d_out;                  // [4,2048,1024] fp32
  char* ws = (char*)d_ws;

  bf16* wqkvT = (bf16*)(ws);                        //  6 MB [3072][1024] permuted bf16
  bf16* woT   = (bf16*)(ws + 6291456);              //  2 MB [1024][1024] bf16
  bf16* xb    = (bf16*)(ws + 8388608);              // 16 MB [8192][1024] bf16
  bf16* Qb    = (bf16*)(ws + 25165824);             // 16 MB [bh][t][d]
  bf16* Kb    = (bf16*)(ws + 41943040);             // 16 MB [bh][t][d]
  bf16* Vb    = (bf16*)(ws + 58720256);             // 16 MB [bh][t][d]
  bf16* VTb   = xb;   // x dead after QKV GEMM; reuse as V-transpose
  bf16* AOb   = Vb;   // V dead after transpose_v; reuse as attention output

  prep_all<<<8576, 256, 0, stream>>>(x, xb, Wqkv, wqkvT, Wo, woT);
  gemm_bt<1><<<dim3(64, 24), 256, 0, stream>>>(xb, wqkvT, nullptr, 3072, Qb, Kb, Vb);
  transpose_v<<<dim3(32, 64), 256, 0, stream>>>(Vb, VTb);
  attn_fwd<<<dim3(64, 16), 256, 0, stream>>>(Qb, Kb, VTb, AOb);
  gemm_bt<0><<<dim3(64, 8), 256, 0, stream>>>(AOb, woT, out, 1024, nullptr, nullptr, nullptr);
}

// Round 8
// 265.218 us; speedup vs baseline: 1.1210x; 1.0132x over previous
//
#include <hip/hip_runtime.h>

typedef __bf16 bf16;
typedef __bf16 bf16x2 __attribute__((ext_vector_type(2)));
typedef __bf16 bf16x4 __attribute__((ext_vector_type(4)));
typedef __bf16 bf16x8 __attribute__((ext_vector_type(8)));
typedef float  f32x4  __attribute__((ext_vector_type(4)));
typedef unsigned int u32;
typedef unsigned int u32x2 __attribute__((ext_vector_type(2)));
typedef unsigned int u32x4 __attribute__((ext_vector_type(4)));

#define LOG2E 1.44269504088896340736f
#define EXP_SC (0.125f * LOG2E)   // folded into Q at the QKV-GEMM epilogue

#if __has_builtin(__builtin_amdgcn_exp2f)
#define EXP2F(x) __builtin_amdgcn_exp2f(x)
#else
#define EXP2F(x) __builtin_exp2f(x)
#endif

// fast f32 -> bf16 (round-half-up) packed pair via v_perm_b32
__device__ __forceinline__ u32 pk_bf16(float lo, float hi) {
  u32 a = __float_as_uint(lo) + 0x8000u;
  u32 b = __float_as_uint(hi) + 0x8000u;
  return __builtin_amdgcn_perm(b, a, 0x07060302);  // [bf16(lo) | bf16(hi)<<16]
}
// packed pair via gfx950 v_cvt_pk_bf16_f32 when available (1 instr, RNE)
#if __has_builtin(__builtin_amdgcn_cvt_pk_bf16_f32)
__device__ __forceinline__ u32 cvtpk(float lo, float hi) {
  bf16x2 t = __builtin_amdgcn_cvt_pk_bf16_f32(lo, hi);
  return __builtin_bit_cast(u32, t);
}
#else
__device__ __forceinline__ u32 cvtpk(float lo, float hi) { return pk_bf16(lo, hi); }
#endif
__device__ __forceinline__ unsigned short bf16r(float x) {
  return (unsigned short)((__float_as_uint(x) + 0x8000u) >> 16);
}

// async global->LDS, 16B per lane. LDS dest = wave-uniform base + lane*16.
__device__ __forceinline__ void async_ld16(void* lds, const void* g) {
  __builtin_amdgcn_global_load_lds(
      (const __attribute__((address_space(1))) void*)(g),
      (__attribute__((address_space(3))) void*)(lds),
      16, 0, 0);
}

// ---------------------------------------------------------------------------
// Fused prep: one launch, three block ranges (phases overlap across CUs).
//   [0, 8192)      : x fp32 -> xb bf16 (4 elems/thread)
//   [8192, 8448)   : WT_perm[n'][k] = bf16(W_qkv[k][orig_n(n')]),
//                    n' = which*1024+h*64+d, orig_n = d*48+which*16+h
//   [8448, 8576)   : WoT[n][k] = bf16(W_o[k][n])
// ---------------------------------------------------------------------------
__global__ void prep_all(const float* __restrict__ x,    bf16* __restrict__ xb,
                         const float* __restrict__ Wqkv, bf16* __restrict__ wqkvT,
                         const float* __restrict__ Wo,   bf16* __restrict__ woT) {
  __shared__ float s[12288];                // 48 KB
  const int bid = blockIdx.x;
  const int tid = threadIdx.x;
  if (bid < 8192) {
    int i = bid * 256 + tid;
    float4 v = ((const float4*)x)[i];
    u32x2 o = { pk_bf16(v.x, v.y), pk_bf16(v.z, v.w) };
    *(u32x2*)(xb + (size_t)i * 4) = o;
  } else if (bid < 8448) {
    const int k0 = (bid - 8192) * 4;
    for (int i = tid; i < 3072; i += 256) {       // 4 rows * 768 float4
      int r = i / 768, c = (i - r * 768) * 4;
      *(float4*)(s + r * 3072 + c) = *(const float4*)(Wqkv + (size_t)(k0 + r) * 3072 + c);
    }
    __syncthreads();
    for (int n = tid; n < 3072; n += 256) {
      int d = n & 63, h = (n >> 6) & 15, wch = n >> 10;
      int on = d * 48 + wch * 16 + h;
      u32x2 v = { pk_bf16(s[0 * 3072 + on], s[1 * 3072 + on]),
                  pk_bf16(s[2 * 3072 + on], s[3 * 3072 + on]) };
      *(u32x2*)(wqkvT + (size_t)n * 1024 + k0) = v;
    }
  } else {
    const int k0 = (bid - 8448) * 8;
    for (int i = tid; i < 2048; i += 256) {       // 8 rows * 256 float4
      int r = i >> 8, c = (i & 255) * 4;
      *(float4*)(s + r * 1024 + c) = *(const float4*)(Wo + (size_t)(k0 + r) * 1024 + c);
    }
    __syncthreads();
    for (int n = tid; n < 1024; n += 256) {
      u32x4 v = { pk_bf16(s[0 * 1024 + n], s[1 * 1024 + n]),
                  pk_bf16(s[2 * 1024 + n], s[3 * 1024 + n]),
                  pk_bf16(s[4 * 1024 + n], s[5 * 1024 + n]),
                  pk_bf16(s[6 * 1024 + n], s[7 * 1024 + n]) };
      *(u32x4*)(woT + (size_t)n * 1024 + k0) = v;
    }
  }
}

// ---------------------------------------------------------------------------
// GEMM: C = A[M][1024] * BT[N][1024]^T, 128x128 tile, BK=64, 4 waves.
// 32 MFMA per barrier pair. Grid (m-blocks, n-blocks): id%8 = m-block%8.
// MODE 0: fp32 C.  MODE 1: scatter bf16 into Q/K/V [b,h,t,d]; Q pre-scaled.
// ---------------------------------------------------------------------------
template <int MODE>
__launch_bounds__(256, 2)
__global__ void gemm_bt(const bf16* __restrict__ A, const bf16* __restrict__ BT,
                        float* __restrict__ C, int N,
                        bf16* __restrict__ Qb, bf16* __restrict__ Kb, bf16* __restrict__ Vb) {
  constexpr int K = 1024;
  __shared__ bf16 sA[128 * 64];             // 16 KB
  __shared__ bf16 sB[128 * 64];             // 16 KB
  const int m0 = blockIdx.x * 128;
  const int n0 = blockIdx.y * 128;
  const int tid = threadIdx.x;
  const int lane = tid & 63;
  const int w = tid >> 6;
  const int wm = (w >> 1) * 64, wn = (w & 1) * 64;
  const int l15 = lane & 15, quad = lane >> 4;

  f32x4 acc[4][4];
  for (int i = 0; i < 4; i++)
    for (int j = 0; j < 4; j++) acc[i][j] = f32x4{0.f, 0.f, 0.f, 0.f};

  const int rT = tid >> 3;
  const int jT = (tid & 7) ^ (rT & 7);
  const bf16* gA = A  + (size_t)(m0 + rT) * K + jT * 8;
  const bf16* gB = BT + (size_t)(n0 + rT) * K + jT * 8;

  for (int k0 = 0; k0 < K; k0 += 64) {
    __syncthreads();
    for (int i = 0; i < 4; i++) {
      async_ld16((void*)(sA + (i * 256 + w * 64) * 8), gA + (size_t)i * 32 * K);
      async_ld16((void*)(sB + (i * 256 + w * 64) * 8), gB + (size_t)i * 32 * K);
    }
    gA += 64; gB += 64;
    __syncthreads();

    for (int kk = 0; kk < 2; kk++) {
      bf16x8 af[4], bfr[4];
      for (int ms = 0; ms < 4; ms++) {
        int r = wm + ms * 16 + l15;
        af[ms] = *(const bf16x8*)(sA + r * 64 + (((kk * 4 + quad) ^ (r & 7)) * 8));
      }
      for (int ns = 0; ns < 4; ns++) {
        int r = wn + ns * 16 + l15;
        bfr[ns] = *(const bf16x8*)(sB + r * 64 + (((kk * 4 + quad) ^ (r & 7)) * 8));
      }
      for (int ms = 0; ms < 4; ms++)
        for (int ns = 0; ns < 4; ns++)
          acc[ms][ns] = __builtin_amdgcn_mfma_f32_16x16x32_bf16(af[ms], bfr[ns], acc[ms][ns], 0, 0, 0);
    }
  }

  if (MODE == 0) {
    for (int ms = 0; ms < 4; ms++)
      for (int ns = 0; ns < 4; ns++)
        for (int r = 0; r < 4; r++) {
          int row = m0 + wm + ms * 16 + quad * 4 + r;
          int col = n0 + wn + ns * 16 + l15;
          C[(size_t)row * N + col] = acc[ms][ns][r];
        }
  } else {
    for (int ms = 0; ms < 4; ms++)
      for (int ns = 0; ns < 4; ns++)
        for (int r = 0; r < 4; r++) {
          int row = m0 + wm + ms * 16 + quad * 4 + r;
          int col = n0 + wn + ns * 16 + l15;
          int b = row >> 11, t = row & 2047;
          int d = col & 63, h = (col >> 6) & 15, wch = col >> 10;
          bf16* dst = (wch == 0) ? Qb : (wch == 1) ? Kb : Vb;
          float v = acc[ms][ns][r] * ((wch == 0) ? EXP_SC : 1.0f);
          ((unsigned short*)dst)[(((size_t)(b * 16 + h)) * 2048 + t) * 64 + d] = bf16r(v);
        }
  }
}

// ---------------------------------------------------------------------------
// V [bh][t][d] -> VTp [bh][d][t'] with keys PERMUTED within each 64-tile:
// VTp[d][kt + k'] = V[kt + invpi(k')][d], invpi(k') = (k'&3)*16 + (k'>>2).
// ---------------------------------------------------------------------------
__global__ void transpose_v(const bf16* __restrict__ V, bf16* __restrict__ VT) {
  __shared__ bf16 s[64 * 66];
  const int bh = blockIdx.y;
  const int t0 = blockIdx.x * 64;
  for (int i = threadIdx.x; i < 512; i += 256) {
    int t = i >> 3, dc = (i & 7) * 8;
    bf16x8 v = *(const bf16x8*)(V + ((size_t)bh * 2048 + t0 + t) * 64 + dc);
    for (int j = 0; j < 8; j++) s[t * 66 + dc + j] = v[j];
  }
  __syncthreads();
  for (int i = threadIdx.x; i < 512; i += 256) {
    int d = i >> 3, tc = (i & 7) * 8;
    bf16x8 v;
    for (int j = 0; j < 8; j++) {
      int kp = tc + j;
      int src = ((kp & 3) * 16) + (kp >> 2);      // invpi
      v[j] = s[src * 66 + d];
    }
    *(bf16x8*)(VT + ((size_t)bh * 64 + d) * 2048 + t0 + tc) = v;
  }
}

// ---------------------------------------------------------------------------
// Flash attention, SOFTWARE-PIPELINED across K-tiles:
//   iter t:  S(t)=QK MFMA | exp/pack(S(t-1)) VALU | PV(t-2) MFMA
// exp's inputs completed a full iteration ago -> VALU runs while the MFMA
// pipe drains S(t)+PV(t-2); the serial chain of R7 is broken.
// sP per-wave DOUBLE buffer (pack t-1 vs PV t-2); sV 4-deep (PV lags staging
// by 3 buffers; 3 mod 4 != 0 so no WAR); sK single. Row sums in VALU (rs),
// reduced once at the end — removes 4 MFMA/tile from the binding pipe.
// Grid: blockIdx.x = bh (XCD-local K/V), blockIdx.y = q-tile.
// ---------------------------------------------------------------------------
__launch_bounds__(256, 2)
__global__ void attn_fwd(const bf16* __restrict__ Q, const bf16* __restrict__ K,
                         const bf16* __restrict__ VT, bf16* __restrict__ O) {
  __shared__ bf16 sK[64 * 64];              //  8 KB  [key][d]
  __shared__ bf16 sV[4][64 * 64];           // 32 KB  [d][key'], 4-deep
  __shared__ bf16 sP[4][2][32 * 64];        // 32 KB  per-wave double P
  const int bh = blockIdx.x;
  const int q0 = blockIdx.y * 128;
  const int tid = threadIdx.x;
  const int lane = tid & 63, w = tid >> 6;
  const int l15 = lane & 15, quad = lane >> 4;

  bf16x8 qf[2][2];
  for (int ms = 0; ms < 2; ms++)
    for (int kk = 0; kk < 2; kk++)
      qf[ms][kk] = *(const bf16x8*)(Q + ((size_t)bh * 2048 + q0 + w * 32 + ms * 16 + l15) * 64 + kk * 32 + quad * 8);

  f32x4 oa[2][4];
  float rs[2][4];
  for (int ms = 0; ms < 2; ms++) {
    for (int ds = 0; ds < 4; ds++) oa[ms][ds] = f32x4{0.f, 0.f, 0.f, 0.f};
    for (int r = 0; r < 4; r++) rs[ms][r] = 0.f;
  }

  // staging geometry: 512 16B chunks/tile; chunk c = w*128+lane (A half),
  // +64 (B half). B half: row+8, same swizzle -> constant elem offsets.
  const int cA = w * 128 + lane;
  const int rA = cA >> 3, jA = (cA & 7) ^ (rA & 7);
  const bf16* gK = K  + ((size_t)bh * 2048 + rA) * 64 + jA * 8;   // B: +512
  const bf16* gV = VT + ((size_t)bh * 64 + rA) * 2048 + jA * 8;   // B: +16384

  // loop-invariant LDS fragment offsets
  int kvo[4][2], pfo[2][2], pwo[2][4];
  for (int ns = 0; ns < 4; ns++)
    for (int kk = 0; kk < 2; kk++) {
      int r = ns * 16 + l15;
      kvo[ns][kk] = r * 64 + (((kk * 4 + quad) ^ (r & 7)) * 8);
    }
  for (int ms = 0; ms < 2; ms++) {
    int r = ms * 16 + l15;
    for (int kk = 0; kk < 2; kk++)
      pfo[ms][kk] = r * 64 + (((kk * 4 + quad) ^ (r & 7)) * 8);
    for (int rr = 0; rr < 4; rr++) {
      int row = ms * 16 + quad * 4 + rr;
      pwo[ms][rr] = row * 64 + (((l15 >> 1) ^ (row & 7)) * 8) + (l15 & 1) * 4;
    }
  }

  auto do_exp = [&](f32x4 (&Sp)[2][4], bf16* pw) {
    for (int ms = 0; ms < 2; ms++)
      for (int r = 0; r < 4; r++) {
        float e0 = EXP2F(Sp[ms][0][r]), e1 = EXP2F(Sp[ms][1][r]);
        float e2 = EXP2F(Sp[ms][2][r]), e3 = EXP2F(Sp[ms][3][r]);
        rs[ms][r] += (e0 + e1) + (e2 + e3);
        u32x2 pk = { cvtpk(e0, e1), cvtpk(e2, e3) };
        *(u32x2*)(pw + pwo[ms][r]) = pk;
      }
  };
  auto do_pv = [&](const bf16* pb, const bf16* vb) {
    bf16x8 vf[4][2];
    for (int ds = 0; ds < 4; ds++)
      for (int kk = 0; kk < 2; kk++)
        vf[ds][kk] = *(const bf16x8*)(vb + kvo[ds][kk]);
    for (int ms = 0; ms < 2; ms++) {
      bf16x8 pf0 = *(const bf16x8*)(pb + pfo[ms][0]);
      bf16x8 pf1 = *(const bf16x8*)(pb + pfo[ms][1]);
      for (int ds = 0; ds < 4; ds++) {
        oa[ms][ds] = __builtin_amdgcn_mfma_f32_16x16x32_bf16(pf0, vf[ds][0], oa[ms][ds], 0, 0, 0);
        oa[ms][ds] = __builtin_amdgcn_mfma_f32_16x16x32_bf16(pf1, vf[ds][1], oa[ms][ds], 0, 0, 0);
      }
    }
  };

  // prologue: stage tile 0 -> sK, sV[0]
  async_ld16((void*)(sK + w * 1024),            gK);
  async_ld16((void*)(sK + w * 1024 + 512),      gK + 512);
  async_ld16((void*)(sV[0] + w * 1024),         gV);
  async_ld16((void*)(sV[0] + w * 1024 + 512),   gV + 16384);
  gK += 4096; gV += 64;

  f32x4 SA[2][4], SB[2][4];

  auto step = [&](int t, f32x4 (&Sc)[2][4], f32x4 (&Sp)[2][4]) {
    __syncthreads();                      // tile t landed in sK / sV[t&3]
    bf16x8 kf[4][2];
    for (int ns = 0; ns < 4; ns++)
      for (int kk = 0; kk < 2; kk++)
        kf[ns][kk] = *(const bf16x8*)(sK + kvo[ns][kk]);
    __syncthreads();                      // all waves read sK -> restage ok
    if (t < 31) {
      bf16* vb = sV[(t + 1) & 3];
      async_ld16((void*)(sK + w * 1024),          gK);
      async_ld16((void*)(sK + w * 1024 + 512),    gK + 512);
      async_ld16((void*)(vb + w * 1024),          gV);
      async_ld16((void*)(vb + w * 1024 + 512),    gV + 16384);
      gK += 4096; gV += 64;
    }
    // D: Sc = Q K^T (tile t) — MFMA issue, results not needed until t+1
    for (int ms = 0; ms < 2; ms++)
      for (int ns = 0; ns < 4; ns++) {
        f32x4 acc0 = f32x4{0.f, 0.f, 0.f, 0.f};
        acc0 = __builtin_amdgcn_mfma_f32_16x16x32_bf16(qf[ms][0], kf[ns][0], acc0, 0, 0, 0);
        acc0 = __builtin_amdgcn_mfma_f32_16x16x32_bf16(qf[ms][1], kf[ns][1], acc0, 0, 0, 0);
        Sc[ms][ns] = acc0;
      }
    // E: exp/pack S(t-1) — inputs completed last iter -> immediate VALU
    if (t >= 1) do_exp(Sp, sP[w][(t - 1) & 1]);
    // F: PV(t-2)
    if (t >= 2) do_pv(sP[w][t & 1], sV[(t - 2) & 3]);
  };

  for (int t = 0; t < 32; t += 2) {       // 2x unroll: S-buffer role swap
    step(t, SA, SB);
    step(t + 1, SB, SA);
  }
  // epilogue: S(31) is in SB
  do_exp(SB, sP[w][1]);                   // pack(31)
  do_pv(sP[w][0], sV[2]);                 // PV(30)
  do_pv(sP[w][1], sV[3]);                 // PV(31)

  // row-sum reduction across the 16 column-lanes (once per kernel)
  const int b = bh >> 4, h = bh & 15;
  for (int ms = 0; ms < 2; ms++)
    for (int r = 0; r < 4; r++) {
      float t = rs[ms][r];
      t += __shfl_xor(t, 1, 64);
      t += __shfl_xor(t, 2, 64);
      t += __shfl_xor(t, 4, 64);
      t += __shfl_xor(t, 8, 64);
      float inv = 1.0f / t;
      int tq = q0 + w * 32 + ms * 16 + quad * 4 + r;
      for (int ds = 0; ds < 4; ds++)
        ((unsigned short*)O)[((size_t)b * 2048 + tq) * 1024 + h * 64 + ds * 16 + l15] =
            bf16r(oa[ms][ds][r] * inv);
    }
}

// ---------------------------------------------------------------------------
extern "C" void kernel_launch(void* const* d_in, const int* in_sizes, int n_in,
                              void* d_out, int out_size, void* d_ws, size_t ws_size,
                              hipStream_t stream) {
  const float* x    = (const float*)d_in[0];   // [4,2048,1024] fp32
  const float* Wqkv = (const float*)d_in[1];   // [1024,3072] fp32
  const float* Wo   = (const float*)d_in[2];   // [1024,1024] fp32
  float* out = (float*)d_out;                  // [4,2048,1024] fp32
  char* ws = (char*)d_ws;

  bf16* wqkvT = (bf16*)(ws);                        //  6 MB [3072][1024] permuted bf16
  bf16* woT   = (bf16*)(ws + 6291456);              //  2 MB [1024][1024] bf16
  bf16* xb    = (bf16*)(ws + 8388608);              // 16 MB [8192][1024] bf16
  bf16* Qb    = (bf16*)(ws + 25165824);             // 16 MB [bh][t][d]
  bf16* Kb    = (bf16*)(ws + 41943040);             // 16 MB [bh][t][d]
  bf16* Vb    = (bf16*)(ws + 58720256);             // 16 MB [bh][t][d]
  bf16* VTb   = xb;   // x dead after QKV GEMM; reuse as V-transpose
  bf16* AOb   = Vb;   // V dead after transpose_v; reuse as attention output

  prep_all<<<8576, 256, 0, stream>>>(x, xb, Wqkv, wqkvT, Wo, woT);
  gemm_bt<1><<<dim3(64, 24), 256, 0, stream>>>(xb, wqkvT, nullptr, 3072, Qb, Kb, Vb);
  transpose_v<<<dim3(32, 64), 256, 0, stream>>>(Vb, VTb);
  attn_fwd<<<dim3(64, 16), 256, 0, stream>>>(Qb, Kb, VTb, AOb);
  gemm_bt<0><<<dim3(64, 8), 256, 0, stream>>>(AOb, woT, out, 1024, nullptr, nullptr, nullptr);
}